// Round 1
// baseline (25.783 us; speedup 1.0000x reference)
//
#include <hip/hip_runtime.h>

// QSP response: per element n with a = w_real[n,0,0], s = w_imag[n,0,1]:
//   state (m0, m1) = column 0 of M (complex), init = RZ(phi0)*H column 0.
//   step k=1..63:  t = W * m  (W = a*I + i*s*X),  m = diag(e^{-i t/2}, e^{+i t/2}) * t
//   out = Re((m0 + m1) / sqrt(2))
// Phase table cos/sin(phi_k/2) is lane-uniform -> LDS, broadcast reads (free).

static constexpr float kInvSqrt2 = 0.70710678118654752440f;

__global__ __launch_bounds__(256) void qsp_kernel(
    const float* __restrict__ phi,
    const float4* __restrict__ w_real,   // [N] float4, .x = a
    const float4* __restrict__ w_imag,   // [N] float4, .y = s
    float* __restrict__ out,
    int n)
{
    __shared__ float cs_tab[64];
    __shared__ float sn_tab[64];
    if (threadIdx.x < 64) {
        float t = 0.5f * phi[threadIdx.x];
        float s, c;
        sincosf(t, &s, &c);
        cs_tab[threadIdx.x] = c;
        sn_tab[threadIdx.x] = s;
    }
    __syncthreads();

    const int i = blockIdx.x * blockDim.x + threadIdx.x;
    if (i >= n) return;

    const float a = w_real[i].x;
    const float s = w_imag[i].y;

    const float c0 = cs_tab[0];
    const float s0 = sn_tab[0];
    float m0r = kInvSqrt2 * c0;
    float m0i = -kInvSqrt2 * s0;
    float m1r = kInvSqrt2 * c0;
    float m1i = kInvSqrt2 * s0;

#pragma unroll
    for (int k = 1; k < 64; ++k) {
        const float c  = cs_tab[k];
        const float sp = sn_tab[k];
        // t = W * m,  W = [[a, i s],[i s, a]]
        const float t0r = fmaf(a, m0r, -s * m1i);
        const float t0i = fmaf(a, m0i,  s * m1r);
        const float t1r = fmaf(a, m1r, -s * m0i);
        const float t1i = fmaf(a, m1i,  s * m0r);
        // m = diag(e^{-i t/2}, e^{+i t/2}) * t
        m0r = fmaf(c, t0r,  sp * t0i);
        m0i = fmaf(c, t0i, -sp * t0r);
        m1r = fmaf(c, t1r, -sp * t1i);
        m1i = fmaf(c, t1i,  sp * t1r);
    }

    out[i] = (m0r + m1r) * kInvSqrt2;
}

extern "C" void kernel_launch(void* const* d_in, const int* in_sizes, int n_in,
                              void* d_out, int out_size, void* d_ws, size_t ws_size,
                              hipStream_t stream) {
    const float*  phi    = (const float*)d_in[0];
    const float4* w_real = (const float4*)d_in[1];  // [N,2,2] f32 -> N float4
    const float4* w_imag = (const float4*)d_in[2];
    float* out = (float*)d_out;

    const int n = in_sizes[1] / 4;   // N elements
    const int block = 256;
    const int grid = (n + block - 1) / block;
    qsp_kernel<<<grid, block, 0, stream>>>(phi, w_real, w_imag, out, n);
}